// Round 3
// baseline (160.544 us; speedup 1.0000x reference)
//
#include <hip/hip_runtime.h>
#include <hip/hip_bf16.h>

#define NPIX 4096
#define NCH  256

typedef __attribute__((ext_vector_type(8))) short short8;
typedef __attribute__((ext_vector_type(16))) float f32x16;
typedef __attribute__((ext_vector_type(8))) int i32x8;

// 4x 8-byte k-chunks -> one K=64 f8f6f4 operand (8 VGPRs)
union Frag64 { long l[4]; i32x8 v; };

#define SC1 0x7F7F7F7F  // E8M0 scale bytes = 127 -> scale 1.0 (all blocks)

// pack 4 f32 -> 4 fp8 e4m3 bytes (OCP on gfx950), byte0=a .. byte3=d
__device__ inline unsigned int pkfp8x4(float a, float b, float c, float d) {
    int w = __builtin_amdgcn_cvt_pk_fp8_f32(a, b, 0, false);
    w = __builtin_amdgcn_cvt_pk_fp8_f32(c, d, w, true);
    return (unsigned int)w;
}

__device__ inline unsigned char fp8b(float a) {
    return (unsigned char)(__builtin_amdgcn_cvt_pk_fp8_f32(a, a, 0, false) & 0xff);
}

__device__ inline float bperm(int srclane, float v) {
    return __int_as_float(__builtin_amdgcn_ds_bpermute(
        srclane << 2, __float_as_int(v)));
}

// ---------------------------------------------------------------------------
// Kernel A (merged): blocks [0,1024): x transpose+bf16; [1024,1344): weights.
//   x -> XT [B][4096][256] bf16;  w -> Wc [320][256] bf16 (+bc f32[320]).
//   K-side rows get 1/sqrt(32)*log2(e) folded in (softmax runs in exp2).
// ---------------------------------------------------------------------------
__global__ void __launch_bounds__(256) prep_kernel(
    const float* __restrict__ x,
    const float* __restrict__ wq, const float* __restrict__ bq,
    const float* __restrict__ wk, const float* __restrict__ bk,
    const float* __restrict__ wv, const float* __restrict__ bv,
    __hip_bfloat16* __restrict__ Wc, float* __restrict__ bc,
    __hip_bfloat16* __restrict__ XTg)
{
    const int bid = blockIdx.x;
    const int t   = threadIdx.x;
    if (bid >= 1024) {
        const int j = bid - 1024;
        const float kQ = 0.17677669529663687f * 1.4426950408889634f;
        const float* src;
        float sc = 1.0f;
        if (j < 32)       { src = wq + j * 256; }
        else if (j < 64)  { src = wk + (j - 32) * 256; sc = kQ; }
        else              { src = wv + (j - 64) * 256; }
        Wc[j * 256 + t] = __float2bfloat16(src[t] * sc);
        if (t == 0) {
            float bb = (j < 32) ? bq[j] : (j < 64) ? bk[j - 32] * kQ : bv[j - 64];
            bc[j] = bb;
        }
        return;
    }
    __shared__ float xs[64][65];
    const int b  = bid >> 8;
    const int c0 = ((bid >> 6) & 3) * 64;
    const int n0 = (bid & 63) * 64;
    const float* xb = x + ((size_t)b * NCH + c0) * NPIX + n0;
    #pragma unroll 4
    for (int i = 0; i < 16; ++i) {
        int c = i * 4 + (t >> 6);
        int n = t & 63;
        xs[c][n] = xb[(size_t)c * NPIX + n];
    }
    __syncthreads();
    #pragma unroll 4
    for (int i = 0; i < 16; ++i) {
        int nn = i * 4 + (t >> 6);
        int cL = t & 63;
        XTg[((size_t)b * NPIX + n0 + nn) * NCH + c0 + cL] =
            __float2bfloat16(xs[cL][nn]);
    }
}

// ---------------------------------------------------------------------------
// Kernel C: QKV projection via MFMA 32x32x16 bf16; OUTPUTS IN FP8 e4m3.
//   Q8,K8: [B][n][32] fp8 (K pre-scaled by 1/sqrt32*log2e).
//   V8 : frag-native [B][n/16][c=256][n%16] fp8 -> 8B/lane PV B-frags.
// grid (32, 2, B) — 256 blocks (1/CU).
// ---------------------------------------------------------------------------
__global__ void __launch_bounds__(256) proj_kernel(
    const __hip_bfloat16* __restrict__ Wc, const float* __restrict__ bc,
    const __hip_bfloat16* __restrict__ XTg,
    unsigned char* __restrict__ Q8, unsigned char* __restrict__ K8,
    unsigned char* __restrict__ V8)
{
    const int b    = blockIdx.z;
    const int t    = threadIdx.x;
    const int lane = t & 63;
    const int wid  = t >> 6;
    const int lo   = lane & 31;
    const int hi   = lane >> 5;
    const int n0   = blockIdx.x * 128 + wid * 32;
    const int jb   = blockIdx.y * 5;

    short8 xf[16];
    const __hip_bfloat16* xr = XTg + ((size_t)b * NPIX + n0 + lo) * NCH;
    #pragma unroll
    for (int ks = 0; ks < 16; ++ks)
        xf[ks] = *(const short8*)(xr + ks * 16 + hi * 8);

    for (int jo = 0; jo < 5; ++jo) {
        const int jt = jb + jo;
        f32x16 acc;
        #pragma unroll
        for (int r = 0; r < 16; ++r) acc[r] = 0.f;
        const __hip_bfloat16* wr = Wc + (size_t)(jt * 32 + lo) * NCH;
        #pragma unroll
        for (int ks = 0; ks < 16; ++ks) {
            short8 wf = *(const short8*)(wr + ks * 16 + hi * 8);
            acc = __builtin_amdgcn_mfma_f32_32x32x16_bf16(wf, xf[ks], acc, 0, 0, 0);
        }
        if (jt < 2) {
            unsigned char* dst = (jt == 0 ? Q8 : K8)
                               + ((size_t)b * NPIX + n0 + lo) * 32;
            #pragma unroll
            for (int g = 0; g < 4; ++g) {
                int jr = 8 * g + 4 * hi;
                unsigned int w = pkfp8x4(acc[4 * g + 0] + bc[jt * 32 + jr + 0],
                                         acc[4 * g + 1] + bc[jt * 32 + jr + 1],
                                         acc[4 * g + 2] + bc[jt * 32 + jr + 2],
                                         acc[4 * g + 3] + bc[jt * 32 + jr + 3]);
                *(unsigned int*)(dst + jr) = w;
            }
        } else {
            unsigned char* vb = V8 + (size_t)b * NPIX * NCH
                              + (size_t)((n0 + lo) >> 4) * 4096 + (lo & 15);
            #pragma unroll
            for (int r = 0; r < 16; ++r) {
                int jr = (r & 3) + 8 * (r >> 2) + 4 * hi;
                int c  = jt * 32 + jr - 64;
                vb[(size_t)c * 16] = fp8b(acc[r] + bc[jt * 32 + jr]);
            }
        }
    }
}

// ---------------------------------------------------------------------------
// Kernel D v3: BARRIER-FREE flash attention + residual + LayerNorm.
// Block = 32-q tile, 4 waves (256 thr), grid (128,4) -> 2 blocks/CU.
// Wave w owns m in [w*1024, w*1024+1024): 16 chunks of 64 m. Per chunk:
//   QK (2x 32x32x16 fp8 MFMA per 32-m half) -> exp2 -> cvt_pk_fp8 +
//   v_permlane32_swap_b32 builds the PV A-frag ENTIRELY IN REGISTERS
//   (lane lo already holds P-row q=lo; only hi-halves need exchange).
//   PV: 8x K=64 MX MFMA into acc[8] (full 32q x 256c partial per wave).
// NO LDS, NO barriers in the main loop — latency hidden by pure ILP +
// 2 waves/SIMD. Epilogue: ds_add_f32 cross-wave O-reduction into obuf,
// then the LN epilogue. ~128 acc VGPRs; launch_bounds(256,2) caps at 256.
// ---------------------------------------------------------------------------
__global__ void __launch_bounds__(256, 2) attn_kernel(
    const unsigned char* __restrict__ Q8, const unsigned char* __restrict__ K8,
    const unsigned char* __restrict__ V8, const __hip_bfloat16* __restrict__ XTg,
    const float* __restrict__ gamma_p, const float* __restrict__ lnw,
    const float* __restrict__ lnb, float* __restrict__ out)
{
    // [0,32768): obuf [32 q][256 c] f32 (reduction target)
    // [0,37888): ybuf [256][37] f32 (epilogue overlay of obuf)
    // [37888,38400): red_s [4][32];  [38400,39424): red2 [32 q][4 w][2]
    __shared__ char smem[39424];

    const int t    = threadIdx.x;
    const int lane = t & 63;
    const int wid  = t >> 6;          // 0..3 : m-range owner
    const int lo   = lane & 31;
    const int hi   = lane >> 5;

    // XCD-aware swizzle: batch b pinned to XCDs {2b, 2b+1}
    const int lid = blockIdx.y * 128 + blockIdx.x;
    const int xcd = lid & 7;
    const int b   = xcd >> 1;
    const int q0  = ((xcd & 1) * 64 + (lid >> 3)) * 32;

    // zero obuf (done before main loop; no smem use until epilogue)
    float4* ob4 = (float4*)smem;
    float4 zz; zz.x = 0.f; zz.y = 0.f; zz.z = 0.f; zz.w = 0.f;
    #pragma unroll
    for (int i = 0; i < 8; ++i) ob4[t + 256 * i] = zz;

    // Q B-frags (32x32x16): col q=lo, k-byte = hi*8+j; two d-halves
    const unsigned char* Qb = Q8 + ((size_t)b * NPIX + q0) * 32;
    const long qf0 = *(const long*)(Qb + lo * 32 + hi * 8);
    const long qf1 = *(const long*)(Qb + lo * 32 + 16 + hi * 8);

    // wave's K rows: m = wid*1024 + ch*64 + half*32 + lo
    const unsigned char* Kp = K8 + (size_t)b * NPIX * 32
                            + ((size_t)wid * 1024 + lo) * 32 + hi * 8;
    // wave's V stream: granule pointers p=0..3 (k-chunk), +cb*512 per c-block
    const unsigned char* vbase = V8 + (size_t)b * NPIX * NCH
                               + ((size_t)wid * 64) * 4096 + lo * 16 + hi * 8;
    const unsigned char* vp0 = vbase;
    const unsigned char* vp1 = vbase + 4096;
    const unsigned char* vp2 = vbase + 8192;
    const unsigned char* vp3 = vbase + 12288;

    f32x16 acc[8];
    #pragma unroll
    for (int cb = 0; cb < 8; ++cb)
        #pragma unroll
        for (int r = 0; r < 16; ++r) acc[cb][r] = 0.f;
    f32x16 z16;
    #pragma unroll
    for (int r = 0; r < 16; ++r) z16[r] = 0.f;
    float s_run = 0.f;

    __syncthreads();   // obuf zeroed (epilogue-only dependency)

    for (int ch = 0; ch < 16; ++ch) {
        // K frags for the two 32-m halves of this chunk
        long kA0a = *(const long*)(Kp);
        long kA1a = *(const long*)(Kp + 16);
        long kA0b = *(const long*)(Kp + 1024);
        long kA1b = *(const long*)(Kp + 1024 + 16);
        Kp += 2048;

        // V B-frags for all 8 c-blocks (issued early; consumed by PV)
        Frag64 vb[8];
        #pragma unroll
        for (int cb = 0; cb < 8; ++cb) {
            vb[cb].l[0] = *(const long*)(vp0 + cb * 512);
            vb[cb].l[1] = *(const long*)(vp1 + cb * 512);
            vb[cb].l[2] = *(const long*)(vp2 + cb * 512);
            vb[cb].l[3] = *(const long*)(vp3 + cb * 512);
        }
        vp0 += 16384; vp1 += 16384; vp2 += 16384; vp3 += 16384;

        // QK^T (swapped): lane lo = q, regs = m-local
        f32x16 s0 = __builtin_amdgcn_mfma_f32_32x32x16_fp8_fp8(kA0a, qf0, z16, 0, 0, 0);
        s0 = __builtin_amdgcn_mfma_f32_32x32x16_fp8_fp8(kA1a, qf1, s0, 0, 0, 0);
        f32x16 s1 = __builtin_amdgcn_mfma_f32_32x32x16_fp8_fp8(kA0b, qf0, z16, 0, 0, 0);
        s1 = __builtin_amdgcn_mfma_f32_32x32x16_fp8_fp8(kA1b, qf1, s1, 0, 0, 0);

        // exp2 -> fp8 -> in-register A-frag via permlane32_swap (T12)
        Frag64 pa;
        float psum = 0.f;
        {
            float e[16];
            #pragma unroll
            for (int r = 0; r < 16; ++r) { e[r] = __builtin_exp2f(s0[r]); psum += e[r]; }
            unsigned int X  = pkfp8x4(e[0], e[1], e[2], e[3]);
            unsigned int Y  = pkfp8x4(e[4], e[5], e[6], e[7]);
            asm("v_permlane32_swap_b32 %0, %1" : "+v"(X), "+v"(Y));
            pa.l[0] = (long)(((unsigned long)Y << 32) | X);
            unsigned int X2 = pkfp8x4(e[8], e[9], e[10], e[11]);
            unsigned int Y2 = pkfp8x4(e[12], e[13], e[14], e[15]);
            asm("v_permlane32_swap_b32 %0, %1" : "+v"(X2), "+v"(Y2));
            pa.l[1] = (long)(((unsigned long)Y2 << 32) | X2);
        }
        {
            float e[16];
            #pragma unroll
            for (int r = 0; r < 16; ++r) { e[r] = __builtin_exp2f(s1[r]); psum += e[r]; }
            unsigned int X  = pkfp8x4(e[0], e[1], e[2], e[3]);
            unsigned int Y  = pkfp8x4(e[4], e[5], e[6], e[7]);
            asm("v_permlane32_swap_b32 %0, %1" : "+v"(X), "+v"(Y));
            pa.l[2] = (long)(((unsigned long)Y << 32) | X);
            unsigned int X2 = pkfp8x4(e[8], e[9], e[10], e[11]);
            unsigned int Y2 = pkfp8x4(e[12], e[13], e[14], e[15]);
            asm("v_permlane32_swap_b32 %0, %1" : "+v"(X2), "+v"(Y2));
            pa.l[3] = (long)(((unsigned long)Y2 << 32) | X2);
        }
        s_run += psum;

        // PV: 8 independent K=64 MFMAs (acc rows = q, cols = c)
        __builtin_amdgcn_s_setprio(1);
        #pragma unroll
        for (int cb = 0; cb < 8; ++cb)
            acc[cb] = __builtin_amdgcn_mfma_scale_f32_32x32x64_f8f6f4(
                pa.v, vb[cb].v, acc[cb], 0, 0, 0, SC1, 0, SC1);
        __builtin_amdgcn_s_setprio(0);
    }

    // ---- cross-wave reduction: O partials into obuf via ds_add_f32 ----
    float* ob     = (float*)smem;
    float* red_sp = (float*)(smem + 37888);       // [4][32]
    float* red2p  = (float*)(smem + 38400);       // [32 q][4 w][2]

    #pragma unroll
    for (int cb = 0; cb < 8; ++cb) {
        #pragma unroll
        for (int r = 0; r < 16; ++r) {
            int qr = (r & 3) + 8 * (r >> 2) + 4 * hi;
            atomicAdd(&ob[qr * 256 + 32 * cb + lo], acc[cb][r]);
        }
    }
    s_run += __shfl_xor(s_run, 32);
    if (hi == 0) red_sp[wid * 32 + lo] = s_run;
    __syncthreads();

    // ---- epilogue: residual + LayerNorm ----
    float stot = red_sp[lo] + red_sp[32 + lo] + red_sp[64 + lo] + red_sp[96 + lo];
    const float invs = 1.0f / stot;
    const float gamma = gamma_p[0];
    const int cL0 = 32 * wid + lo;
    const int cL1 = cL0 + 128;
    const __hip_bfloat16* XTb = XTg + ((size_t)b * NPIX + q0) * NCH;
    float rv[2][16];
    #pragma unroll
    for (int r = 0; r < 16; ++r) {
        int qr = (r & 3) + 8 * (r >> 2) + 4 * hi;
        float ir = bperm(qr, invs);
        float o0 = ob[qr * 256 + cL0];
        float o1 = ob[qr * 256 + cL1];
        float x0 = __bfloat162float(XTb[(size_t)qr * NCH + cL0]);
        float x1 = __bfloat162float(XTb[(size_t)qr * NCH + cL1]);
        rv[0][r] = gamma * (o0 * ir) + x0;
        rv[1][r] = gamma * (o1 * ir) + x1;
        float s1v = rv[0][r] + rv[1][r];
        float s2v = rv[0][r] * rv[0][r] + rv[1][r] * rv[1][r];
        #pragma unroll
        for (int off = 1; off < 32; off <<= 1) {
            s1v += __shfl_xor(s1v, off);
            s2v += __shfl_xor(s2v, off);
        }
        if (lo == 0) {
            red2p[qr * 8 + wid * 2]     = s1v;
            red2p[qr * 8 + wid * 2 + 1] = s2v;
        }
    }
    __syncthreads();   // red2 ready; obuf reads complete (ybuf may overlay)
    float sA = 0.f, sB = 0.f;
    #pragma unroll
    for (int w = 0; w < 4; ++w) {
        sA += red2p[lo * 8 + w * 2];
        sB += red2p[lo * 8 + w * 2 + 1];
    }
    const float mean = sA * (1.f / 256.f);
    const float var  = sB * (1.f / 256.f) - mean * mean;
    const float rstd = rsqrtf(var + 1e-5f);
    const float lw0 = lnw[cL0], lb0 = lnb[cL0];
    const float lw1 = lnw[cL1], lb1 = lnb[cL1];
    float (*ybuf)[37] = (float(*)[37])smem;       // overlays obuf, pad 37
    #pragma unroll
    for (int r = 0; r < 16; ++r) {
        int qr = (r & 3) + 8 * (r >> 2) + 4 * hi;
        float m  = bperm(qr, mean);
        float rr = bperm(qr, rstd);
        ybuf[cL0][qr] = (rv[0][r] - m) * rr * lw0 + lb0;
        ybuf[cL1][qr] = (rv[1][r] - m) * rr * lw1 + lb1;
    }
    __syncthreads();
    // store: thread t owns c-row t, 32 q's (128 B contiguous per row)
    float* dst = out + ((size_t)b * NCH + t) * NPIX + q0;
    #pragma unroll
    for (int j = 0; j < 8; ++j) {
        float4 v;
        v.x = ybuf[t][j * 4 + 0];
        v.y = ybuf[t][j * 4 + 1];
        v.z = ybuf[t][j * 4 + 2];
        v.w = ybuf[t][j * 4 + 3];
        *(float4*)(dst + j * 4) = v;
    }
}

// ---------------------------------------------------------------------------
extern "C" void kernel_launch(void* const* d_in, const int* in_sizes, int n_in,
                              void* d_out, int out_size, void* d_ws, size_t ws_size,
                              hipStream_t stream) {
    const float* x     = (const float*)d_in[0];
    const float* wq    = (const float*)d_in[1];
    const float* bq    = (const float*)d_in[2];
    const float* wk    = (const float*)d_in[3];
    const float* bk    = (const float*)d_in[4];
    const float* wv    = (const float*)d_in[5];
    const float* bv    = (const float*)d_in[6];
    const float* gamma = (const float*)d_in[7];
    const float* ln_w  = (const float*)d_in[8];
    const float* ln_b  = (const float*)d_in[9];
    float* out = (float*)d_out;

    const int B = 4;
    unsigned char* ws = (unsigned char*)d_ws;
    unsigned char*  Q8 = ws;                                   // 512 KB
    unsigned char*  K8 = ws + (512u << 10);                    // 512 KB
    unsigned char*  V8 = ws + (1u << 20);                      // 4 MB
    __hip_bfloat16* XT = (__hip_bfloat16*)(ws + (5u << 20));   // 8 MB
    __hip_bfloat16* Wc = (__hip_bfloat16*)(ws + (13u << 20));  // 160 KB
    float*          bc = (float*)(ws + (13u << 20) + 163840);  // 1.25 KB

    prep_kernel<<<dim3(1344), 256, 0, stream>>>(x, wq, bq, wk, bk, wv, bv,
                                                Wc, bc, XT);
    proj_kernel<<<dim3(32, 2, B), 256, 0, stream>>>(Wc, bc, XT, Q8, K8, V8);
    attn_kernel<<<dim3(128, B), 256, 0, stream>>>(Q8, K8, V8, XT, gamma,
                                                  ln_w, ln_b, out);
}

// Round 4
// 87.775 us; speedup vs baseline: 1.8290x; 1.8290x over previous
//
#include <hip/hip_runtime.h>
#include <hip/hip_bf16.h>

#define NPIX 4096
#define NCH  256

typedef __attribute__((ext_vector_type(8))) short short8;
typedef __attribute__((ext_vector_type(16))) float f32x16;
typedef __attribute__((ext_vector_type(8))) int i32x8;

// 4x 8-byte k-chunks -> one K=64 f8f6f4 operand (8 VGPRs)
union Frag64 { long l[4]; i32x8 v; };

#define SC1 0x7F7F7F7F  // E8M0 scale bytes = 127 -> scale 1.0 (all blocks)

// pack 4 f32 -> 4 fp8 e4m3 bytes (OCP on gfx950), byte0=a .. byte3=d
__device__ inline unsigned int pkfp8x4(float a, float b, float c, float d) {
    int w = __builtin_amdgcn_cvt_pk_fp8_f32(a, b, 0, false);
    w = __builtin_amdgcn_cvt_pk_fp8_f32(c, d, w, true);
    return (unsigned int)w;
}

__device__ inline unsigned char fp8b(float a) {
    return (unsigned char)(__builtin_amdgcn_cvt_pk_fp8_f32(a, a, 0, false) & 0xff);
}

__device__ inline float bperm(int srclane, float v) {
    return __int_as_float(__builtin_amdgcn_ds_bpermute(
        srclane << 2, __float_as_int(v)));
}

// Barrier WITHOUT the vmcnt(0) drain __syncthreads would emit: only LDS
// (lgkmcnt) ordering is needed for the ps handoff; global register loads
// stay in flight across phases (their consumers are guarded by the
// compiler's own scoreboard waitcnt). sched_barrier fences stop the
// compiler from moving memory ops across the asm (rule #18).
__device__ inline void barrier_nodrain() {
    __builtin_amdgcn_sched_barrier(0);
    asm volatile("s_waitcnt lgkmcnt(0)" ::: "memory");
    __builtin_amdgcn_s_barrier();
    __builtin_amdgcn_sched_barrier(0);
}

// ---------------------------------------------------------------------------
// Kernel A (merged): blocks [0,1024): x transpose+bf16; [1024,1344): weights.
//   x -> XT [B][4096][256] bf16;  w -> Wc [320][256] bf16 (+bc f32[320]).
//   K-side rows get 1/sqrt(32)*log2(e) folded in (softmax runs in exp2).
// ---------------------------------------------------------------------------
__global__ void __launch_bounds__(256) prep_kernel(
    const float* __restrict__ x,
    const float* __restrict__ wq, const float* __restrict__ bq,
    const float* __restrict__ wk, const float* __restrict__ bk,
    const float* __restrict__ wv, const float* __restrict__ bv,
    __hip_bfloat16* __restrict__ Wc, float* __restrict__ bc,
    __hip_bfloat16* __restrict__ XTg)
{
    const int bid = blockIdx.x;
    const int t   = threadIdx.x;
    if (bid >= 1024) {
        const int j = bid - 1024;
        const float kQ = 0.17677669529663687f * 1.4426950408889634f;
        const float* src;
        float sc = 1.0f;
        if (j < 32)       { src = wq + j * 256; }
        else if (j < 64)  { src = wk + (j - 32) * 256; sc = kQ; }
        else              { src = wv + (j - 64) * 256; }
        Wc[j * 256 + t] = __float2bfloat16(src[t] * sc);
        if (t == 0) {
            float bb = (j < 32) ? bq[j] : (j < 64) ? bk[j - 32] * kQ : bv[j - 64];
            bc[j] = bb;
        }
        return;
    }
    __shared__ float xs[64][65];
    const int b  = bid >> 8;
    const int c0 = ((bid >> 6) & 3) * 64;
    const int n0 = (bid & 63) * 64;
    const float* xb = x + ((size_t)b * NCH + c0) * NPIX + n0;
    #pragma unroll 4
    for (int i = 0; i < 16; ++i) {
        int c = i * 4 + (t >> 6);
        int n = t & 63;
        xs[c][n] = xb[(size_t)c * NPIX + n];
    }
    __syncthreads();
    #pragma unroll 4
    for (int i = 0; i < 16; ++i) {
        int nn = i * 4 + (t >> 6);
        int cL = t & 63;
        XTg[((size_t)b * NPIX + n0 + nn) * NCH + c0 + cL] =
            __float2bfloat16(xs[cL][nn]);
    }
}

// ---------------------------------------------------------------------------
// Kernel C: QKV projection via MFMA 32x32x16 bf16; OUTPUTS IN FP8 e4m3.
//   Q8,K8: [B][n][32] fp8 (K pre-scaled by 1/sqrt32*log2e).
//   V8 : frag-native [B][n/16][c=256][n%16] fp8 -> 8B/lane PV B-frags.
// grid (32, 2, B) — 256 blocks (1/CU).
// ---------------------------------------------------------------------------
__global__ void __launch_bounds__(256) proj_kernel(
    const __hip_bfloat16* __restrict__ Wc, const float* __restrict__ bc,
    const __hip_bfloat16* __restrict__ XTg,
    unsigned char* __restrict__ Q8, unsigned char* __restrict__ K8,
    unsigned char* __restrict__ V8)
{
    const int b    = blockIdx.z;
    const int t    = threadIdx.x;
    const int lane = t & 63;
    const int wid  = t >> 6;
    const int lo   = lane & 31;
    const int hi   = lane >> 5;
    const int n0   = blockIdx.x * 128 + wid * 32;
    const int jb   = blockIdx.y * 5;

    short8 xf[16];
    const __hip_bfloat16* xr = XTg + ((size_t)b * NPIX + n0 + lo) * NCH;
    #pragma unroll
    for (int ks = 0; ks < 16; ++ks)
        xf[ks] = *(const short8*)(xr + ks * 16 + hi * 8);

    for (int jo = 0; jo < 5; ++jo) {
        const int jt = jb + jo;
        f32x16 acc;
        #pragma unroll
        for (int r = 0; r < 16; ++r) acc[r] = 0.f;
        const __hip_bfloat16* wr = Wc + (size_t)(jt * 32 + lo) * NCH;
        #pragma unroll
        for (int ks = 0; ks < 16; ++ks) {
            short8 wf = *(const short8*)(wr + ks * 16 + hi * 8);
            acc = __builtin_amdgcn_mfma_f32_32x32x16_bf16(wf, xf[ks], acc, 0, 0, 0);
        }
        if (jt < 2) {
            unsigned char* dst = (jt == 0 ? Q8 : K8)
                               + ((size_t)b * NPIX + n0 + lo) * 32;
            #pragma unroll
            for (int g = 0; g < 4; ++g) {
                int jr = 8 * g + 4 * hi;
                unsigned int w = pkfp8x4(acc[4 * g + 0] + bc[jt * 32 + jr + 0],
                                         acc[4 * g + 1] + bc[jt * 32 + jr + 1],
                                         acc[4 * g + 2] + bc[jt * 32 + jr + 2],
                                         acc[4 * g + 3] + bc[jt * 32 + jr + 3]);
                *(unsigned int*)(dst + jr) = w;
            }
        } else {
            unsigned char* vb = V8 + (size_t)b * NPIX * NCH
                              + (size_t)((n0 + lo) >> 4) * 4096 + (lo & 15);
            #pragma unroll
            for (int r = 0; r < 16; ++r) {
                int jr = (r & 3) + 8 * (r >> 2) + 4 * hi;
                int c  = jt * 32 + jr - 64;
                vb[(size_t)c * 16] = fp8b(acc[r] + bc[jt * 32 + jr]);
            }
        }
    }
}

// ---------------------------------------------------------------------------
// Kernel D: flash attention (fp8 K=64 MX MFMA) + residual + LayerNorm, fused.
// Block = 32-q tile, 8 waves (512 thr), 2 blocks/CU. Software-pipelined:
// phase it runs {QK(it) || PV(it-1)} on the MFMA pipe, exp(it) on VALU,
// V(it) loads stay IN FLIGHT across the barrier (barrier_nodrain: lgkmcnt
// only, no vmcnt(0) drain — V/K loads feed registers, not LDS, so the
// ps handoff needs only ds-write retirement + s_barrier).
// MFMA = K=64 MX-scaled f8f6f4, unit scales (numerics == non-scaled fp8).
// No max subtraction (exp2 domain). grid (128, 4).
// ---------------------------------------------------------------------------
__global__ void __launch_bounds__(512, 4) attn_kernel(
    const unsigned char* __restrict__ Q8, const unsigned char* __restrict__ K8,
    const unsigned char* __restrict__ V8, const __hip_bfloat16* __restrict__ XTg,
    const float* __restrict__ gamma_p, const float* __restrict__ lnw,
    const float* __restrict__ lnb, float* __restrict__ out)
{
    // [0,16384): ps dbuf 2 x [32 q][256 m] fp8, 8B-granule XOR swizzle
    // [0,36864): ybuf[256][36] f32 (epilogue overlay of ps)
    // [36864,37888): red_s [8][32];  [37888,39936): red2 [32 q][8 w][2]
    __shared__ char smem[39936];

    const int t    = threadIdx.x;
    const int lane = t & 63;
    const int wid  = t >> 6;          // 0..7
    const int lo   = lane & 31;
    const int hi   = lane >> 5;

    // XCD-aware swizzle: batch b pinned to XCDs {2b, 2b+1}
    const int lid = blockIdx.y * 128 + blockIdx.x;
    const int xcd = lid & 7;
    const int b   = xcd >> 1;
    const int q0  = ((xcd & 1) * 64 + (lid >> 3)) * 32;

    // Q B-frag (K=64, upper 32 k zero-padded): col q=lo, k-byte = hi*8+j
    const unsigned char* Qb = Q8 + ((size_t)b * NPIX + q0) * 32;
    Frag64 qv;
    qv.l[0] = *(const long*)(Qb + lo * 32 + hi * 8);
    qv.l[1] = *(const long*)(Qb + lo * 32 + 16 + hi * 8);
    qv.l[2] = 0; qv.l[3] = 0;

    // wave's K chunk: rows m = it*256 + wid*32 + lo
    const unsigned char* Kw = K8 + (size_t)b * NPIX * 32
                            + (size_t)(wid * 32 + lo) * 32 + hi * 8;
    // wave's V stream: c = 32*wid + lo, bytes m%16 = hi*8+j
    const unsigned char* Vw = V8 + (size_t)b * NPIX * NCH
                            + (size_t)(32 * wid + lo) * 16 + hi * 8;

    f32x16 acc;
    #pragma unroll
    for (int r = 0; r < 16; ++r) acc[r] = 0.f;
    f32x16 z16;
    #pragma unroll
    for (int r = 0; r < 16; ++r) z16[r] = 0.f;
    float s_run = 0.f;

    const int swz = lo & 15;

    // K frag (persistent, upper 32 k zero)
    Frag64 ka;
    ka.l[0] = *(const long*)(Kw);
    ka.l[1] = *(const long*)(Kw + 16);
    ka.l[2] = 0; ka.l[3] = 0;
    long kB0 = 0, kB1 = 0;

    // V frags for phase 0 (chunk-native: vva[s] feeds one K=64 MFMA)
    Frag64 vva[4];
    #pragma unroll
    for (int s = 0; s < 4; ++s)
        #pragma unroll
        for (int p = 0; p < 4; ++p)
            vva[s].l[p] = *(const long*)(Vw + (size_t)(4 * s + p) * 4096);

    // ---- prologue phase 0: QK(0) + exp(0) -> ps[0] ----
    {
        f32x16 sct = __builtin_amdgcn_mfma_scale_f32_32x32x64_f8f6f4(
            ka.v, qv.v, z16, 0, 0, 0, SC1, 0, SC1);
        kB0 = *(const long*)(Kw + 8192);
        kB1 = *(const long*)(Kw + 8192 + 16);
        char* pb = smem + lo * 256 + 4 * hi;
        float psum = 0.f;
        #pragma unroll
        for (int g = 0; g < 4; ++g) {
            float e0 = __builtin_exp2f(sct[4 * g + 0]);
            float e1 = __builtin_exp2f(sct[4 * g + 1]);
            float e2 = __builtin_exp2f(sct[4 * g + 2]);
            float e3 = __builtin_exp2f(sct[4 * g + 3]);
            psum += (e0 + e1) + (e2 + e3);
            unsigned int w = pkfp8x4(e0, e1, e2, e3);
            int gran = (4 * wid + g) ^ swz;
            *(unsigned int*)(pb + gran * 8) = w;
        }
        psum += __shfl_xor(psum, 32);
        s_run += psum;
    }
    barrier_nodrain();

    // ---- pipelined phases 1..15: QK(it) || PV(it-1), exp(it), V(it) ----
    for (int it = 1; it < 16; ++it) {
        ka.l[0] = kB0; ka.l[1] = kB1;
        // QK(it): issue first on the MFMA pipe (independent of LDS)
        f32x16 sct = __builtin_amdgcn_mfma_scale_f32_32x32x64_f8f6f4(
            ka.v, qv.v, z16, 0, 0, 0, SC1, 0, SC1);

        // PV(it-1): A = P frags from ps[(it-1)&1], B = vva (regs)
        const char* pr = smem + ((it - 1) & 1) * 8192 + lo * 256;
        __builtin_amdgcn_s_setprio(1);
        #pragma unroll
        for (int s = 0; s < 4; ++s) {
            Frag64 pa;
            #pragma unroll
            for (int p = 0; p < 4; ++p) {
                int gran = (8 * s + 2 * p + hi) ^ swz;
                pa.l[p] = *(const long*)(pr + gran * 8);
            }
            acc = __builtin_amdgcn_mfma_scale_f32_32x32x64_f8f6f4(
                pa.v, vva[s].v, acc, 0, 0, 0, SC1, 0, SC1);
        }
        __builtin_amdgcn_s_setprio(0);

        // K prefetch for it+1
        if (it < 15) {
            kB0 = *(const long*)(Kw + (size_t)(it + 1) * 8192);
            kB1 = *(const long*)(Kw + (size_t)(it + 1) * 8192 + 16);
        }

        // V(it) loads (consumed by PV(it) next phase; may land across the
        // barrier — no drain)
        const unsigned char* vit = Vw + (size_t)it * 65536;
        #pragma unroll
        for (int s = 0; s < 4; ++s)
            #pragma unroll
            for (int p = 0; p < 4; ++p)
                vva[s].l[p] = *(const long*)(vit + (size_t)(4 * s + p) * 4096);

        // exp(it) -> ps[it&1] (other parity than PV just read)
        char* pb = smem + (it & 1) * 8192 + lo * 256 + 4 * hi;
        float psum = 0.f;
        #pragma unroll
        for (int g = 0; g < 4; ++g) {
            float e0 = __builtin_exp2f(sct[4 * g + 0]);
            float e1 = __builtin_exp2f(sct[4 * g + 1]);
            float e2 = __builtin_exp2f(sct[4 * g + 2]);
            float e3 = __builtin_exp2f(sct[4 * g + 3]);
            psum += (e0 + e1) + (e2 + e3);
            unsigned int w = pkfp8x4(e0, e1, e2, e3);
            int gran = (4 * wid + g) ^ swz;
            *(unsigned int*)(pb + gran * 8) = w;
        }
        psum += __shfl_xor(psum, 32);
        s_run += psum;

        barrier_nodrain();
    }

    // ---- tail: PV(15) ----
    {
        const char* pr = smem + 8192 + lo * 256;  // ps[15&1 = 1]
        __builtin_amdgcn_s_setprio(1);
        #pragma unroll
        for (int s = 0; s < 4; ++s) {
            Frag64 pa;
            #pragma unroll
            for (int p = 0; p < 4; ++p) {
                int gran = (8 * s + 2 * p + hi) ^ swz;
                pa.l[p] = *(const long*)(pr + gran * 8);
            }
            acc = __builtin_amdgcn_mfma_scale_f32_32x32x64_f8f6f4(
                pa.v, vva[s].v, acc, 0, 0, 0, SC1, 0, SC1);
        }
        __builtin_amdgcn_s_setprio(0);
    }

    // ---- epilogue ----
    float* red_sp = (float*)(smem + 36864);       // [8][32]
    float* red2p  = (float*)(smem + 37888);       // [32 q][8 w][2]
    float (*ybuf)[36] = (float(*)[36])smem;       // overlays ps

    if (hi == 0) red_sp[wid * 32 + lo] = s_run;
    __syncthreads();
    float stot = 0.f;
    #pragma unroll
    for (int w = 0; w < 8; ++w) stot += red_sp[w * 32 + lo];
    const float invs = 1.0f / stot;
    const float gamma = gamma_p[0];
    const int cL = 32 * wid + lo;
    const __hip_bfloat16* XTb = XTg + ((size_t)b * NPIX + q0) * NCH + cL;
    float rv[16];
    #pragma unroll
    for (int r = 0; r < 16; ++r) {
        int qr = (r & 3) + 8 * (r >> 2) + 4 * hi;
        float ir = bperm(qr, invs);
        float xv = __bfloat162float(XTb[(size_t)qr * NCH]);
        rv[r] = gamma * (acc[r] * ir) + xv;
        float s1 = rv[r];
        float s2 = rv[r] * rv[r];
        #pragma unroll
        for (int off = 1; off < 32; off <<= 1) {
            s1 += __shfl_xor(s1, off);
            s2 += __shfl_xor(s2, off);
        }
        if (lo == 0) {
            red2p[qr * 16 + wid * 2]     = s1;
            red2p[qr * 16 + wid * 2 + 1] = s2;
        }
    }
    __syncthreads();
    float sA = 0.f, sB = 0.f;
    #pragma unroll
    for (int w = 0; w < 8; ++w) {
        sA += red2p[lo * 16 + w * 2];
        sB += red2p[lo * 16 + w * 2 + 1];
    }
    const float mean = sA * (1.f / 256.f);
    const float var  = sB * (1.f / 256.f) - mean * mean;
    const float rstd = rsqrtf(var + 1e-5f);
    const float lwv = lnw[cL];
    const float lbv = lnb[cL];
    #pragma unroll
    for (int r = 0; r < 16; ++r) {
        int qr = (r & 3) + 8 * (r >> 2) + 4 * hi;
        float m  = bperm(qr, mean);
        float rr = bperm(qr, rstd);
        ybuf[cL][qr] = (rv[r] - m) * rr * lwv + lbv;
    }
    __syncthreads();
    // coalesced store: thread pair per c-row, 16 q's each
    const int c_r = t >> 1;
    const int qh  = (t & 1) * 16;
    float* dst = out + ((size_t)b * NCH + c_r) * NPIX + q0 + qh;
    #pragma unroll
    for (int j = 0; j < 4; ++j) {
        float4 v;
        v.x = ybuf[c_r][qh + j * 4 + 0];
        v.y = ybuf[c_r][qh + j * 4 + 1];
        v.z = ybuf[c_r][qh + j * 4 + 2];
        v.w = ybuf[c_r][qh + j * 4 + 3];
        *(float4*)(dst + j * 4) = v;
    }
}

// ---------------------------------------------------------------------------
extern "C" void kernel_launch(void* const* d_in, const int* in_sizes, int n_in,
                              void* d_out, int out_size, void* d_ws, size_t ws_size,
                              hipStream_t stream) {
    const float* x     = (const float*)d_in[0];
    const float* wq    = (const float*)d_in[1];
    const float* bq    = (const float*)d_in[2];
    const float* wk    = (const float*)d_in[3];
    const float* bk    = (const float*)d_in[4];
    const float* wv    = (const float*)d_in[5];
    const float* bv    = (const float*)d_in[6];
    const float* gamma = (const float*)d_in[7];
    const float* ln_w  = (const float*)d_in[8];
    const float* ln_b  = (const float*)d_in[9];
    float* out = (float*)d_out;

    const int B = 4;
    unsigned char* ws = (unsigned char*)d_ws;
    unsigned char*  Q8 = ws;                                   // 512 KB
    unsigned char*  K8 = ws + (512u << 10);                    // 512 KB
    unsigned char*  V8 = ws + (1u << 20);                      // 4 MB
    __hip_bfloat16* XT = (__hip_bfloat16*)(ws + (5u << 20));   // 8 MB
    __hip_bfloat16* Wc = (__hip_bfloat16*)(ws + (13u << 20));  // 160 KB
    float*          bc = (float*)(ws + (13u << 20) + 163840);  // 1.25 KB

    prep_kernel<<<dim3(1344), 256, 0, stream>>>(x, wq, bq, wk, bk, wv, bv,
                                                Wc, bc, XT);
    proj_kernel<<<dim3(32, 2, B), 256, 0, stream>>>(Wc, bc, XT, Q8, K8, V8);
    attn_kernel<<<dim3(128, B), 512, 0, stream>>>(Q8, K8, V8, XT, gamma,
                                                  ln_w, ln_b, out);
}